// Round 1
// baseline (326.412 us; speedup 1.0000x reference)
//
#include <hip/hip_runtime.h>

#define H 1024
#define W 1024
#define NIMG 32
#define NOFF 16
#define TH 32
#define TW 64
#define LROWS (TH + 7)   // 39
#define LCOLS 80         // stride (78 used)

// offsets in output order: d in {1,3,5,7} x theta in {0,45,90,135}
// (orow, ocol) = (round(sin*d), round(cos*d))
__constant__ int c_orow[NOFF] = {0,1,1,1, 0,2,3,2, 0,4,5,4, 0,5,7,5};
__constant__ int c_ocol[NOFF] = {1,1,0,-1, 3,2,0,-2, 5,4,0,-4, 7,5,0,-5};

__global__ __launch_bounds__(256)
void minmax_partial(const float* __restrict__ x, float* __restrict__ pmn, float* __restrict__ pmx) {
    int img = blockIdx.y;
    int chunk = blockIdx.x;             // 64 chunks of 16384 floats
    const float4* b4 = (const float4*)(x + (size_t)img * (H * (size_t)W) + (size_t)chunk * (H * W / 64));
    int tid = threadIdx.x;
    float mn = INFINITY, mx = -INFINITY;
    for (int i = tid; i < 4096; i += 256) {
        float4 v = b4[i];
        mn = fminf(mn, fminf(fminf(v.x, v.y), fminf(v.z, v.w)));
        mx = fmaxf(mx, fmaxf(fmaxf(v.x, v.y), fmaxf(v.z, v.w)));
    }
    for (int o = 32; o > 0; o >>= 1) {
        mn = fminf(mn, __shfl_down(mn, o, 64));
        mx = fmaxf(mx, __shfl_down(mx, o, 64));
    }
    __shared__ float smn[4], smx[4];
    int wave = tid >> 6, lane = tid & 63;
    if (lane == 0) { smn[wave] = mn; smx[wave] = mx; }
    __syncthreads();
    if (tid == 0) {
        mn = fminf(fminf(smn[0], smn[1]), fminf(smn[2], smn[3]));
        mx = fmaxf(fmaxf(smx[0], smx[1]), fmaxf(smx[2], smx[3]));
        pmn[img * 64 + chunk] = mn;
        pmx[img * 64 + chunk] = mx;
    }
}

__global__ __launch_bounds__(64)
void minmax_final(const float* __restrict__ pmn, const float* __restrict__ pmx,
                  float* __restrict__ mnmx, unsigned long long* __restrict__ acc) {
    int img = blockIdx.x;
    int t = threadIdx.x;  // 64 = 1 wave
    float mn = pmn[img * 64 + t], mx = pmx[img * 64 + t];
    for (int o = 32; o > 0; o >>= 1) {
        mn = fminf(mn, __shfl_down(mn, o, 64));
        mx = fmaxf(mx, __shfl_down(mx, o, 64));
    }
    if (t == 0) { mnmx[img * 2] = mn; mnmx[img * 2 + 1] = mx; }
    if (t < NOFF) acc[img * NOFF + t] = 0ull;   // ws is poisoned each launch
}

__global__ __launch_bounds__(256)
void glcm_contrast(const float* __restrict__ x, const float* __restrict__ mnmx,
                   unsigned long long* __restrict__ acc) {
    constexpr int ORO[NOFF] = {0,1,1,1, 0,2,3,2, 0,4,5,4, 0,5,7,5};
    constexpr int OCO[NOFF] = {1,1,0,-1, 3,2,0,-2, 5,4,0,-4, 7,5,0,-5};
    int img = blockIdx.z;
    int gr0 = blockIdx.y * TH;
    int gc0 = blockIdx.x * TW - 7;      // LDS col 0 <-> global col gc0
    __shared__ int tile[LROWS * LCOLS];
    float mn = mnmx[img * 2], mx = mnmx[img * 2 + 1];
    float range = mx - mn;
    const float* xi = x + (size_t)img * (H * (size_t)W);
    int tid = threadIdx.x;
    // load 39 rows x 78 cols (+halo), quantize exactly like the reference:
    // trunc( (255*(v-mn)) / (mx-mn) )
    for (int i = tid; i < LROWS * LCOLS; i += 256) {
        int r = i / LCOLS;
        int c = i - r * LCOLS;
        int grr = gr0 + r, gcc = gc0 + c;
        if (c < 78 && grr < H && gcc >= 0 && gcc < W) {
            float v = xi[grr * W + gcc];
            tile[i] = (int)((255.0f * (v - mn)) / range);
        }
    }
    __syncthreads();

    int lx = tid & 63;       // 0..63  -> a col = gc0+7+lx (always in-image)
    int ly0 = tid >> 6;      // 0..3
    int gc = gc0 + 7 + lx;
    int accs[NOFF];
#pragma unroll
    for (int k = 0; k < NOFF; k++) accs[k] = 0;
#pragma unroll
    for (int yy = 0; yy < 8; yy++) {
        int ly = ly0 + yy * 4;           // 0..31
        int gr = gr0 + ly;
        int a = tile[ly * LCOLS + 7 + lx];
#pragma unroll
        for (int k = 0; k < NOFF; k++) {
            int b = tile[(ly + ORO[k]) * LCOLS + 7 + lx + OCO[k]];
            int d = a - b;
            bool valid = (gr + ORO[k] < H) && ((unsigned)(gc + OCO[k]) < (unsigned)W);
            accs[k] += valid ? d * d : 0;
        }
    }
    // wave reduce each accumulator, then cross-wave via LDS
#pragma unroll
    for (int k = 0; k < NOFF; k++) {
        int v = accs[k];
        for (int o = 32; o > 0; o >>= 1) v += __shfl_down(v, o, 64);
        accs[k] = v;
    }
    __shared__ int red[4][NOFF];
    if ((tid & 63) == 0) {
#pragma unroll
        for (int k = 0; k < NOFF; k++) red[tid >> 6][k] = accs[k];
    }
    __syncthreads();
    if (tid < NOFF) {
        unsigned long long s = (unsigned long long)(
            (long long)red[0][tid] + red[1][tid] + red[2][tid] + red[3][tid]);
        atomicAdd(&acc[img * NOFF + tid], s);
    }
}

__global__ __launch_bounds__(512)
void finalize(const unsigned long long* __restrict__ acc, float* __restrict__ out) {
    int t = threadIdx.x;
    if (t >= NIMG * NOFF) return;
    int k = t & 15;
    int orow = c_orow[k];
    int ocol = c_ocol[k];
    int aoc = ocol < 0 ? -ocol : ocol;
    double n = (double)(H - orow) * (double)(W - aoc);
    out[t] = (float)((double)acc[t] / n);
}

extern "C" void kernel_launch(void* const* d_in, const int* in_sizes, int n_in,
                              void* d_out, int out_size, void* d_ws, size_t ws_size,
                              hipStream_t stream) {
    const float* x = (const float*)d_in[0];
    float* out = (float*)d_out;
    char* ws = (char*)d_ws;
    float* pmn = (float*)ws;                          // 2048 floats
    float* pmx = pmn + NIMG * 64;                     // 2048 floats
    float* mnmx = pmx + NIMG * 64;                    // 64 floats
    unsigned long long* acc = (unsigned long long*)(ws + 32 * 1024);  // 512 u64

    minmax_partial<<<dim3(64, NIMG), 256, 0, stream>>>(x, pmn, pmx);
    minmax_final<<<NIMG, 64, 0, stream>>>(pmn, pmx, mnmx, acc);
    glcm_contrast<<<dim3(W / TW, H / TH, NIMG), 256, 0, stream>>>(x, mnmx, acc);
    finalize<<<1, 512, 0, stream>>>(acc, out);
}

// Round 2
// 318.920 us; speedup vs baseline: 1.0235x; 1.0235x over previous
//
#include <hip/hip_runtime.h>

#define H 1024
#define W 1024
#define NIMG 32
#define NOFF 16
#define NACC 17          // 16 cross terms + 1 sum(s^2)
#define TH 32            // owned rows per block
#define TW 256           // owned cols per block
#define TROWS 39         // 32 + 7 halo rows (down only)
#define TSTR 304         // LDS row stride bytes (16-aligned, 76 words == 12 mod 32: bank-uniform)

__device__ __forceinline__ int sdot4i(unsigned a, unsigned b, int c) {
#if __has_builtin(__builtin_amdgcn_sdot4)
    return __builtin_amdgcn_sdot4((int)a, (int)b, c, false);
#else
    c += (int)(signed char)(a)       * (int)(signed char)(b);
    c += (int)(signed char)(a >> 8)  * (int)(signed char)(b >> 8);
    c += (int)(signed char)(a >> 16) * (int)(signed char)(b >> 16);
    c += (int)(signed char)(a >> 24) * (int)(signed char)(b >> 24);
    return c;
#endif
}

// dot of 32 'a' pixels (aw[0..7]) against window bytes starting at S=16+4m+OC
template <int OC>
__device__ __forceinline__ int dot8(const unsigned* w, const unsigned* aw, int acc) {
#pragma unroll
    for (int m = 0; m < 8; ++m) {
        const int S = 16 + 4 * m + OC;
        unsigned b;
        if ((S & 3) == 0) {
            b = w[S >> 2];
        } else {
            unsigned long long pair =
                (((unsigned long long)w[(S >> 2) + 1]) << 32) | w[S >> 2];
            b = (unsigned)(pair >> ((S & 3) * 8));   // v_alignbit
        }
        acc = sdot4i(aw[m], b, acc);
    }
    return acc;
}

__device__ __forceinline__ unsigned pack4(float4 f, float s, float b) {
    unsigned q0 = (unsigned)(int)fmaf(f.x, s, b);
    unsigned q1 = (unsigned)(int)fmaf(f.y, s, b);
    unsigned q2 = (unsigned)(int)fmaf(f.z, s, b);
    unsigned q3 = (unsigned)(int)fmaf(f.w, s, b);
    // bytes are q; ^0x80 == (q-128) as signed byte
    return (((q0 & 255u)) | ((q1 & 255u) << 8) | ((q2 & 255u) << 16) | ((q3 & 255u) << 24)) ^ 0x80808080u;
}

// ---------------- kernel 1: per-image min/max partials + zero accumulators ----
__global__ __launch_bounds__(256)
void minmax_partial(const float* __restrict__ x, float* __restrict__ pmn,
                    float* __restrict__ pmx, unsigned long long* __restrict__ gacc) {
    int img = blockIdx.y;
    int chunk = blockIdx.x;             // 64 chunks of 16384 floats
    int tid = threadIdx.x;
    if (chunk == 0 && tid < NACC) gacc[img * NACC + tid] = 0ull;  // ws is poisoned
    const float4* b4 = (const float4*)(x + (size_t)img * (H * (size_t)W) +
                                       (size_t)chunk * (H * W / 64));
    float mn = INFINITY, mx = -INFINITY;
    for (int i = tid; i < 4096; i += 256) {
        float4 v = b4[i];
        mn = fminf(mn, fminf(fminf(v.x, v.y), fminf(v.z, v.w)));
        mx = fmaxf(mx, fmaxf(fmaxf(v.x, v.y), fmaxf(v.z, v.w)));
    }
    for (int o = 32; o > 0; o >>= 1) {
        mn = fminf(mn, __shfl_down(mn, o, 64));
        mx = fmaxf(mx, __shfl_down(mx, o, 64));
    }
    __shared__ float smn[4], smx[4];
    int wave = tid >> 6, lane = tid & 63;
    if (lane == 0) { smn[wave] = mn; smx[wave] = mx; }
    __syncthreads();
    if (tid == 0) {
        mn = fminf(fminf(smn[0], smn[1]), fminf(smn[2], smn[3]));
        mx = fmaxf(fmaxf(smx[0], smx[1]), fmaxf(smx[2], smx[3]));
        pmn[img * 64 + chunk] = mn;
        pmx[img * 64 + chunk] = mx;
    }
}

// ---------------- kernel 2: finalize min/max + band/corner corrections --------
__global__ __launch_bounds__(256)
void mmfinal_corr(const float* __restrict__ x, const float* __restrict__ pmn,
                  const float* __restrict__ pmx, float* __restrict__ mnscale,
                  long long* __restrict__ corrE) {
    __shared__ float sms[2];
    __shared__ int RowS[14], ColS[14];
    __shared__ int craw[4][49];
    __shared__ int cps[4][8][8];
    int img = blockIdx.x;
    int tid = threadIdx.x;
    if (tid < 64) {
        float mn = pmn[img * 64 + tid], mx = pmx[img * 64 + tid];
        for (int o = 32; o > 0; o >>= 1) {
            mn = fminf(mn, __shfl_down(mn, o, 64));
            mx = fmaxf(mx, __shfl_down(mx, o, 64));
        }
        if (tid == 0) {
            float scale = 255.0f / (mx - mn);
            float nmb = -mn * scale;
            sms[0] = scale; sms[1] = nmb;
            mnscale[img * 2] = scale;
            mnscale[img * 2 + 1] = nmb;
        }
    }
    if (tid < 14) { RowS[tid] = 0; ColS[tid] = 0; }
    __syncthreads();
    float scale = sms[0], nmb = sms[1];
    const float* xi = x + (size_t)img * (H * (size_t)W);
    // top-7 / bottom-7 row band sums of s^2
    for (int idx = tid; idx < 14 * W; idx += 256) {
        int r14 = idx >> 10, col = idx & (W - 1);
        int row = r14 < 7 ? r14 : (H - 14 + r14);
        int q = (int)fmaf(xi[(size_t)row * W + col], scale, nmb) - 128;
        atomicAdd(&RowS[r14], q * q);
    }
    // left-7 / right-7 col band sums of s^2
    for (int idx = tid; idx < 14 * H; idx += 256) {
        int c14 = idx >> 10, row = idx & (H - 1);
        int col = c14 < 7 ? c14 : (W - 14 + c14);
        int q = (int)fmaf(xi[(size_t)row * W + col], scale, nmb) - 128;
        atomicAdd(&ColS[c14], q * q);
    }
    // 7x7 corner patches (0=TL,1=TR,2=BL,3=BR), oriented toward the corner
    if (tid < 196) {
        int c4 = tid / 49, p = tid - c4 * 49, i = p / 7, j = p - (p / 7) * 7;
        int row = (c4 & 2) ? (H - 1 - i) : i;
        int col = (c4 & 1) ? (W - 1 - j) : j;
        int q = (int)fmaf(xi[(size_t)row * W + col], scale, nmb) - 128;
        craw[c4][i * 7 + j] = q * q;
    }
    __syncthreads();
    if (tid < 4) {   // 2D prefix: cps[c][r][cc] = sum_{i<r,j<cc} craw
        for (int r = 0; r < 8; ++r)
            for (int c = 0; c < 8; ++c) {
                int v = 0;
                if (r && c)
                    v = cps[tid][r - 1][c] + cps[tid][r][c - 1] - cps[tid][r - 1][c - 1]
                        + craw[tid][(r - 1) * 7 + (c - 1)];
                else
                    v = 0;
                cps[tid][r][c] = v;
            }
    }
    __syncthreads();
    if (tid < NOFF) {
        const int ORO[16] = {0,1,1,1, 0,2,3,2, 0,4,5,4, 0,5,7,5};
        const int OCO[16] = {1,1,0,-1, 3,2,0,-2, 5,4,0,-4, 7,5,0,-5};
        int orr = ORO[tid], oc = OCO[tid], aoc = oc < 0 ? -oc : oc;
        long long RT = 0, RB = 0, CL = 0, CR = 0;
        for (int i = 0; i < orr; ++i) { RT += RowS[i]; RB += RowS[13 - i]; }
        for (int i = 0; i < aoc; ++i) { CL += ColS[i]; CR += ColS[13 - i]; }
        long long CA = oc > 0 ? CR : CL;   // excluded cols of a-region
        long long CB = oc > 0 ? CL : CR;   // excluded cols of b-region
        long long PSa = (oc >= 0) ? cps[3][orr][aoc] : cps[2][orr][aoc]; // BR : BL
        long long PSb = (oc >= 0) ? cps[0][orr][aoc] : cps[1][orr][aoc]; // TL : TR
        corrE[img * NOFF + tid] = -(RT + RB + CA + CB) + PSa + PSb;
    }
}

// ---------------- kernel 3: cross terms + total s^2 via sdot4 -----------------
__global__ __launch_bounds__(256)
void glcm_main(const float* __restrict__ x, const float* __restrict__ mnscale,
               unsigned long long* __restrict__ gacc) {
    __shared__ __align__(16) unsigned char tile[TROWS * TSTR];
    __shared__ int accsh[4][NACC];
    int tid = threadIdx.x;
    int img = blockIdx.z;
    int gr0 = blockIdx.y * TH;
    int gc0 = blockIdx.x * TW;
    float scale = mnscale[img * 2];
    float nmb = mnscale[img * 2 + 1];
    if (tid < 4 * NACC) ((int*)accsh)[tid] = 0;
    const float* xi = x + (size_t)img * (H * (size_t)W);

    // stage rows gr0..gr0+38; LDS byte col c <-> global col gc0-16+c; zero pad OOB
    for (int slot = tid; slot < TROWS * (TSTR / 16); slot += 256) {
        int rr = slot / (TSTR / 16);
        int cc = (slot - rr * (TSTR / 16)) * 16;
        int grow = gr0 + rr;
        int gcol = gc0 - 16 + cc;
        uint4 bytes = make_uint4(0u, 0u, 0u, 0u);
        if (grow < H && gcol >= 0 && gcol < W) {
            const float4* p = (const float4*)(xi + (size_t)grow * W + gcol);
            float4 f0 = p[0], f1 = p[1], f2 = p[2], f3 = p[3];
            bytes.x = pack4(f0, scale, nmb);
            bytes.y = pack4(f1, scale, nmb);
            bytes.z = pack4(f2, scale, nmb);
            bytes.w = pack4(f3, scale, nmb);
        }
        *(uint4*)(tile + rr * TSTR + cc) = bytes;
    }
    __syncthreads();

    int r = tid >> 3;             // 0..31
    int c0 = (tid & 7) * 32;      // 0..224
    const unsigned char* rowp = tile + r * TSTR + 16 + c0;   // 'a' pixels
    const unsigned char* wbase = tile + r * TSTR + c0;       // window byte S=0

    unsigned aw[8];
    *(uint4*)(aw)     = *(const uint4*)(rowp);
    *(uint4*)(aw + 4) = *(const uint4*)(rowp + 16);

    int acc[NOFF];
#pragma unroll
    for (int k = 0; k < NOFF; ++k) acc[k] = 0;
    int t2 = 0;
#pragma unroll
    for (int m = 0; m < 8; ++m) t2 = sdot4i(aw[m], aw[m], t2);

    unsigned w[16];
    // delta = 0 : oc = 1,3,5,7  (w[4..11] == aw)
    {
#pragma unroll
        for (int i = 0; i < 8; ++i) w[4 + i] = aw[i];
        *(uint4*)(w + 12) = *(const uint4*)(wbase + 48);
        acc[0]  = dot8<1>(w, aw, acc[0]);
        acc[4]  = dot8<3>(w, aw, acc[4]);
        acc[8]  = dot8<5>(w, aw, acc[8]);
        acc[12] = dot8<7>(w, aw, acc[12]);
    }
    // delta = 1 : oc = 1,0,-1
    {
        const unsigned char* wp = wbase + 1 * TSTR;
        *(uint4*)(w)      = *(const uint4*)(wp);
        *(uint4*)(w + 4)  = *(const uint4*)(wp + 16);
        *(uint4*)(w + 8)  = *(const uint4*)(wp + 32);
        *(uint4*)(w + 12) = *(const uint4*)(wp + 48);
        acc[1] = dot8<1>(w, aw, acc[1]);
        acc[2] = dot8<0>(w, aw, acc[2]);
        acc[3] = dot8<-1>(w, aw, acc[3]);
    }
    // delta = 2 : oc = 2,-2
    {
        const unsigned char* wp = wbase + 2 * TSTR;
        *(uint4*)(w)      = *(const uint4*)(wp);
        *(uint4*)(w + 4)  = *(const uint4*)(wp + 16);
        *(uint4*)(w + 8)  = *(const uint4*)(wp + 32);
        *(uint4*)(w + 12) = *(const uint4*)(wp + 48);
        acc[5] = dot8<2>(w, aw, acc[5]);
        acc[7] = dot8<-2>(w, aw, acc[7]);
    }
    // delta = 3 : oc = 0 (only w[4..11])
    {
        const unsigned char* wp = wbase + 3 * TSTR;
        *(uint4*)(w + 4) = *(const uint4*)(wp + 16);
        *(uint4*)(w + 8) = *(const uint4*)(wp + 32);
        acc[6] = dot8<0>(w, aw, acc[6]);
    }
    // delta = 4 : oc = 4,-4
    {
        const unsigned char* wp = wbase + 4 * TSTR;
        *(uint4*)(w)      = *(const uint4*)(wp);
        *(uint4*)(w + 4)  = *(const uint4*)(wp + 16);
        *(uint4*)(w + 8)  = *(const uint4*)(wp + 32);
        *(uint4*)(w + 12) = *(const uint4*)(wp + 48);
        acc[9]  = dot8<4>(w, aw, acc[9]);
        acc[11] = dot8<-4>(w, aw, acc[11]);
    }
    // delta = 5 : oc = 0,5,-5
    {
        const unsigned char* wp = wbase + 5 * TSTR;
        *(uint4*)(w)      = *(const uint4*)(wp);
        *(uint4*)(w + 4)  = *(const uint4*)(wp + 16);
        *(uint4*)(w + 8)  = *(const uint4*)(wp + 32);
        *(uint4*)(w + 12) = *(const uint4*)(wp + 48);
        acc[10] = dot8<0>(w, aw, acc[10]);
        acc[13] = dot8<5>(w, aw, acc[13]);
        acc[15] = dot8<-5>(w, aw, acc[15]);
    }
    // delta = 7 : oc = 0 (only w[4..11])
    {
        const unsigned char* wp = wbase + 7 * TSTR;
        *(uint4*)(w + 4) = *(const uint4*)(wp + 16);
        *(uint4*)(w + 8) = *(const uint4*)(wp + 32);
        acc[14] = dot8<0>(w, aw, acc[14]);
    }

    int wv = tid >> 6;
#pragma unroll
    for (int k = 0; k < NOFF; ++k) atomicAdd(&accsh[wv][k], acc[k]);
    atomicAdd(&accsh[wv][16], t2);
    __syncthreads();
    if (tid < NACC) {
        int s = accsh[0][tid] + accsh[1][tid] + accsh[2][tid] + accsh[3][tid];
        atomicAdd(&gacc[img * NACC + tid], (unsigned long long)(long long)s);
    }
}

// ---------------- kernel 4: combine ------------------------------------------
__global__ __launch_bounds__(512)
void finalize_k(const unsigned long long* __restrict__ gacc,
                const long long* __restrict__ corrE, float* __restrict__ out) {
    int t = threadIdx.x;
    if (t >= NIMG * NOFF) return;
    const int ORO[16] = {0,1,1,1, 0,2,3,2, 0,4,5,4, 0,5,7,5};
    const int OCO[16] = {1,1,0,-1, 3,2,0,-2, 5,4,0,-4, 7,5,0,-5};
    int img = t >> 4, k = t & 15;
    long long cross = (long long)gacc[img * NACC + k];
    long long tsum  = (long long)gacc[img * NACC + 16];
    long long num = 2 * tsum + corrE[t] - 2 * cross;
    int orr = ORO[k], aoc = OCO[k] < 0 ? -OCO[k] : OCO[k];
    double n = (double)(H - orr) * (double)(W - aoc);
    out[t] = (float)((double)num / n);
}

extern "C" void kernel_launch(void* const* d_in, const int* in_sizes, int n_in,
                              void* d_out, int out_size, void* d_ws, size_t ws_size,
                              hipStream_t stream) {
    const float* x = (const float*)d_in[0];
    float* out = (float*)d_out;
    char* ws = (char*)d_ws;
    float* pmn = (float*)ws;                                   // 2048 floats
    float* pmx = (float*)(ws + 8192);                          // 2048 floats
    float* mnscale = (float*)(ws + 16384);                     // 64 floats
    unsigned long long* gacc = (unsigned long long*)(ws + 16640);  // 32*17 u64
    long long* corrE = (long long*)(ws + 20992);               // 512 i64

    minmax_partial<<<dim3(64, NIMG), 256, 0, stream>>>(x, pmn, pmx, gacc);
    mmfinal_corr<<<NIMG, 256, 0, stream>>>(x, pmn, pmx, mnscale, corrE);
    glcm_main<<<dim3(W / TW, H / TH, NIMG), 256, 0, stream>>>(x, mnscale, gacc);
    finalize_k<<<1, 512, 0, stream>>>(gacc, corrE, out);
}

// Round 3
// 293.803 us; speedup vs baseline: 1.1110x; 1.0855x over previous
//
#include <hip/hip_runtime.h>

#define H 1024
#define W 1024
#define NIMG 32
#define NOFF 16
#define NACC 17          // 16 cross terms + 1 sum(s^2)
#define TH 32            // owned rows per block
#define TW 256           // owned cols per block
#define TROWS 39         // 32 + 7 halo rows (down only)
#define TSTR 304         // LDS row stride bytes

__device__ __forceinline__ int sdot4i(unsigned a, unsigned b, int c) {
#if __has_builtin(__builtin_amdgcn_sdot4)
    return __builtin_amdgcn_sdot4((int)a, (int)b, c, false);
#else
    c += (int)(signed char)(a)       * (int)(signed char)(b);
    c += (int)(signed char)(a >> 8)  * (int)(signed char)(b >> 8);
    c += (int)(signed char)(a >> 16) * (int)(signed char)(b >> 16);
    c += (int)(signed char)(a >> 24) * (int)(signed char)(b >> 24);
    return c;
#endif
}

__device__ __forceinline__ unsigned funnel(unsigned hi, unsigned lo, int shiftBytes) {
#if __has_builtin(__builtin_amdgcn_alignbit)
    return __builtin_amdgcn_alignbit(hi, lo, shiftBytes * 8);
#else
    unsigned long long pair = (((unsigned long long)hi) << 32) | lo;
    return (unsigned)(pair >> (shiftBytes * 8));
#endif
}

// dot of 32 'a' pixels (aw[0..7]) against window bytes starting at S=16+4m+OC.
// All w/aw indices are compile-time constants after unroll -> stays in VGPRs.
template <int OC>
__device__ __forceinline__ int dot8(const unsigned* w, const unsigned* aw, int acc) {
#pragma unroll
    for (int m = 0; m < 8; ++m) {
        const int S = 16 + 4 * m + OC;
        unsigned b;
        if ((S & 3) == 0) b = w[S >> 2];
        else              b = funnel(w[(S >> 2) + 1], w[S >> 2], S & 3);
        acc = sdot4i(aw[m], b, acc);
    }
    return acc;
}

// scalar-component assignment only (no vector punning into scalar arrays!)
__device__ __forceinline__ void load16w(const unsigned char* wp, unsigned* w) {
    uint4 t0 = *(const uint4*)(wp);
    uint4 t1 = *(const uint4*)(wp + 16);
    uint4 t2 = *(const uint4*)(wp + 32);
    uint4 t3 = *(const uint4*)(wp + 48);
    w[0] = t0.x;  w[1] = t0.y;  w[2] = t0.z;  w[3] = t0.w;
    w[4] = t1.x;  w[5] = t1.y;  w[6] = t1.z;  w[7] = t1.w;
    w[8] = t2.x;  w[9] = t2.y;  w[10] = t2.z; w[11] = t2.w;
    w[12] = t3.x; w[13] = t3.y; w[14] = t3.z; w[15] = t3.w;
}

__device__ __forceinline__ void load8mid(const unsigned char* wp, unsigned* w) {
    uint4 t1 = *(const uint4*)(wp + 16);
    uint4 t2 = *(const uint4*)(wp + 32);
    w[4] = t1.x;  w[5] = t1.y;  w[6] = t1.z;  w[7] = t1.w;
    w[8] = t2.x;  w[9] = t2.y;  w[10] = t2.z; w[11] = t2.w;
}

__device__ __forceinline__ unsigned pack4(float4 f, float s, float b) {
    unsigned q0 = (unsigned)(int)fmaf(f.x, s, b);
    unsigned q1 = (unsigned)(int)fmaf(f.y, s, b);
    unsigned q2 = (unsigned)(int)fmaf(f.z, s, b);
    unsigned q3 = (unsigned)(int)fmaf(f.w, s, b);
    return (((q0 & 255u)) | ((q1 & 255u) << 8) | ((q2 & 255u) << 16) | ((q3 & 255u) << 24)) ^ 0x80808080u;
}

// ---------------- kernel 1: per-image min/max partials + zero all ws accums ---
__global__ __launch_bounds__(256)
void minmax_partial(const float* __restrict__ x, float* __restrict__ pmn,
                    float* __restrict__ pmx, unsigned long long* __restrict__ gacc,
                    int* __restrict__ RowS, int* __restrict__ ColS) {
    int img = blockIdx.y;
    int chunk = blockIdx.x;             // 64 chunks of 16384 floats
    int tid = threadIdx.x;
    if (chunk == 0) {                   // ws is poisoned each launch: zero here
        if (tid < NACC) gacc[img * NACC + tid] = 0ull;
        if (tid >= 32 && tid < 46) RowS[img * 14 + tid - 32] = 0;
        if (tid >= 64 && tid < 78) ColS[img * 14 + tid - 64] = 0;
    }
    const float4* b4 = (const float4*)(x + (size_t)img * (H * (size_t)W) +
                                       (size_t)chunk * (H * W / 64));
    float mn = INFINITY, mx = -INFINITY;
    for (int i = tid; i < 4096; i += 256) {
        float4 v = b4[i];
        mn = fminf(mn, fminf(fminf(v.x, v.y), fminf(v.z, v.w)));
        mx = fmaxf(mx, fmaxf(fmaxf(v.x, v.y), fmaxf(v.z, v.w)));
    }
    for (int o = 32; o > 0; o >>= 1) {
        mn = fminf(mn, __shfl_down(mn, o, 64));
        mx = fmaxf(mx, __shfl_down(mx, o, 64));
    }
    __shared__ float smn[4], smx[4];
    int wave = tid >> 6, lane = tid & 63;
    if (lane == 0) { smn[wave] = mn; smx[wave] = mx; }
    __syncthreads();
    if (tid == 0) {
        mn = fminf(fminf(smn[0], smn[1]), fminf(smn[2], smn[3]));
        mx = fmaxf(fmaxf(smx[0], smx[1]), fmaxf(smx[2], smx[3]));
        pmn[img * 64 + chunk] = mn;
        pmx[img * 64 + chunk] = mx;
    }
}

// ---------------- kernel 2: finalize min/max -> scale, bias -------------------
__global__ __launch_bounds__(64)
void minmax_final(const float* __restrict__ pmn, const float* __restrict__ pmx,
                  float* __restrict__ mnscale) {
    int img = blockIdx.x;
    int t = threadIdx.x;
    float mn = pmn[img * 64 + t], mx = pmx[img * 64 + t];
    for (int o = 32; o > 0; o >>= 1) {
        mn = fminf(mn, __shfl_down(mn, o, 64));
        mx = fmaxf(mx, __shfl_down(mx, o, 64));
    }
    if (t == 0) {
        float scale = 255.0f / (mx - mn);
        mnscale[img * 2] = scale;
        mnscale[img * 2 + 1] = -mn * scale;
    }
}

// ---------------- kernel 3: border band sums of s^2 (parallel) ----------------
__global__ __launch_bounds__(256)
void band_sums(const float* __restrict__ x, const float* __restrict__ mnscale,
               int* __restrict__ RowS, int* __restrict__ ColS) {
    __shared__ int sRow[14], sCol[14];
    int img = blockIdx.y;
    int blk = blockIdx.x;           // 16 blocks of 64 rows each
    int tid = threadIdx.x;
    if (tid < 14) { sRow[tid] = 0; sCol[tid] = 0; }
    __syncthreads();
    float scale = mnscale[img * 2], nmb = mnscale[img * 2 + 1];
    const float* xi = x + (size_t)img * (H * (size_t)W);
    int r0 = blk * 64;
    // col bands: 64 rows x 14 cols
    for (int idx = tid; idx < 64 * 14; idx += 256) {
        int row = r0 + (idx / 14);
        int j = idx - (idx / 14) * 14;
        int col = j < 7 ? j : (W - 14 + j);
        int q = (int)fmaf(xi[(size_t)row * W + col], scale, nmb) - 128;
        atomicAdd(&sCol[j], q * q);
    }
    // row bands: block 0 -> rows 0..6 (RowS[0..6]); block 15 -> rows H-7..H-1 (RowS[7..13])
    if (blk == 0 || blk == 15) {
        int base = (blk == 0) ? 0 : (H - 7);
        int ridx0 = (blk == 0) ? 0 : 7;
        for (int idx = tid; idx < 7 * W; idx += 256) {
            int rr = idx >> 10, col = idx & (W - 1);
            int q = (int)fmaf(xi[(size_t)(base + rr) * W + col], scale, nmb) - 128;
            atomicAdd(&sRow[ridx0 + rr], q * q);
        }
    }
    __syncthreads();
    if (tid < 14) {
        if (sCol[tid]) atomicAdd(&ColS[img * 14 + tid], sCol[tid]);
        if (sRow[tid]) atomicAdd(&RowS[img * 14 + tid], sRow[tid]);
    }
}

// ---------------- kernel 4: cross terms + total s^2 via sdot4 -----------------
__global__ __launch_bounds__(256)
void glcm_main(const float* __restrict__ x, const float* __restrict__ mnscale,
               unsigned long long* __restrict__ gacc) {
    __shared__ __align__(16) unsigned char tile[TROWS * TSTR];
    __shared__ int accsh[4][NACC];
    int tid = threadIdx.x;
    int img = blockIdx.z;
    int gr0 = blockIdx.y * TH;
    int gc0 = blockIdx.x * TW;
    float scale = mnscale[img * 2];
    float nmb = mnscale[img * 2 + 1];
    if (tid < 4 * NACC) ((int*)accsh)[tid] = 0;
    const float* xi = x + (size_t)img * (H * (size_t)W);

    // stage rows gr0..gr0+38; LDS byte col c <-> global col gc0-16+c; zero pad OOB
    for (int slot = tid; slot < TROWS * (TSTR / 16); slot += 256) {
        int rr = slot / (TSTR / 16);
        int cc = (slot - rr * (TSTR / 16)) * 16;
        int grow = gr0 + rr;
        int gcol = gc0 - 16 + cc;
        uint4 bytes = make_uint4(0u, 0u, 0u, 0u);
        if (grow < H && gcol >= 0 && gcol < W) {
            const float4* p = (const float4*)(xi + (size_t)grow * W + gcol);
            float4 f0 = p[0], f1 = p[1], f2 = p[2], f3 = p[3];
            bytes.x = pack4(f0, scale, nmb);
            bytes.y = pack4(f1, scale, nmb);
            bytes.z = pack4(f2, scale, nmb);
            bytes.w = pack4(f3, scale, nmb);
        }
        *(uint4*)(tile + rr * TSTR + cc) = bytes;
    }
    __syncthreads();

    int r = tid >> 3;             // 0..31
    int c0 = (tid & 7) * 32;      // 0..224
    const unsigned char* rowp = tile + r * TSTR + 16 + c0;   // 'a' pixels
    const unsigned char* wbase = tile + r * TSTR + c0;       // window byte S=0

    uint4 av0 = *(const uint4*)(rowp);
    uint4 av1 = *(const uint4*)(rowp + 16);
    unsigned aw[8];
    aw[0] = av0.x; aw[1] = av0.y; aw[2] = av0.z; aw[3] = av0.w;
    aw[4] = av1.x; aw[5] = av1.y; aw[6] = av1.z; aw[7] = av1.w;

    int acc[NOFF];
#pragma unroll
    for (int k = 0; k < NOFF; ++k) acc[k] = 0;
    int t2 = 0;
#pragma unroll
    for (int m = 0; m < 8; ++m) t2 = sdot4i(aw[m], aw[m], t2);

    unsigned w[16];
    // delta = 0 : oc = 1,3,5,7  (w[4..11] == aw; need w[12..13] for oc=7)
    {
        w[0] = 0; w[1] = 0; w[2] = 0; w[3] = 0;
#pragma unroll
        for (int i = 0; i < 8; ++i) w[4 + i] = aw[i];
        uint4 t3 = *(const uint4*)(wbase + 48);
        w[12] = t3.x; w[13] = t3.y; w[14] = t3.z; w[15] = t3.w;
        acc[0]  = dot8<1>(w, aw, acc[0]);
        acc[4]  = dot8<3>(w, aw, acc[4]);
        acc[8]  = dot8<5>(w, aw, acc[8]);
        acc[12] = dot8<7>(w, aw, acc[12]);
    }
    // delta = 1 : oc = 1,0,-1
    {
        load16w(wbase + 1 * TSTR, w);
        acc[1] = dot8<1>(w, aw, acc[1]);
        acc[2] = dot8<0>(w, aw, acc[2]);
        acc[3] = dot8<-1>(w, aw, acc[3]);
    }
    // delta = 2 : oc = 2,-2
    {
        load16w(wbase + 2 * TSTR, w);
        acc[5] = dot8<2>(w, aw, acc[5]);
        acc[7] = dot8<-2>(w, aw, acc[7]);
    }
    // delta = 3 : oc = 0
    {
        load8mid(wbase + 3 * TSTR, w);
        acc[6] = dot8<0>(w, aw, acc[6]);
    }
    // delta = 4 : oc = 4,-4
    {
        load16w(wbase + 4 * TSTR, w);
        acc[9]  = dot8<4>(w, aw, acc[9]);
        acc[11] = dot8<-4>(w, aw, acc[11]);
    }
    // delta = 5 : oc = 0,5,-5
    {
        load16w(wbase + 5 * TSTR, w);
        acc[10] = dot8<0>(w, aw, acc[10]);
        acc[13] = dot8<5>(w, aw, acc[13]);
        acc[15] = dot8<-5>(w, aw, acc[15]);
    }
    // delta = 7 : oc = 0
    {
        load8mid(wbase + 7 * TSTR, w);
        acc[14] = dot8<0>(w, aw, acc[14]);
    }

    int wv = tid >> 6;
#pragma unroll
    for (int k = 0; k < NOFF; ++k) atomicAdd(&accsh[wv][k], acc[k]);
    atomicAdd(&accsh[wv][16], t2);
    __syncthreads();
    if (tid < NACC) {
        int s = accsh[0][tid] + accsh[1][tid] + accsh[2][tid] + accsh[3][tid];
        atomicAdd(&gacc[img * NACC + tid], (unsigned long long)(long long)s);
    }
}

// ---------------- kernel 5: corners + combine ---------------------------------
__global__ __launch_bounds__(512)
void finalize_k(const float* __restrict__ x, const float* __restrict__ mnscale,
                const unsigned long long* __restrict__ gacc,
                const int* __restrict__ RowS, const int* __restrict__ ColS,
                float* __restrict__ out) {
    // corner patches for ALL images: craw[img][c][i*7+j], c: 0=TL,1=TR,2=BL,3=BR
    __shared__ int cps[NIMG][4][8][8];
    __shared__ int craw[NIMG][4][49];
    int tid = threadIdx.x;
    // 32 img * 4 corners * 49 px = 6272 loads
    for (int idx = tid; idx < NIMG * 4 * 49; idx += 512) {
        int img = idx / 196;
        int rem = idx - img * 196;
        int c4 = rem / 49, p = rem - c4 * 49, i = p / 7, j = p - (p / 7) * 7;
        int row = (c4 & 2) ? (H - 1 - i) : i;
        int col = (c4 & 1) ? (W - 1 - j) : j;
        float scale = mnscale[img * 2], nmb = mnscale[img * 2 + 1];
        const float* xi = x + (size_t)img * (H * (size_t)W);
        int q = (int)fmaf(xi[(size_t)row * W + col], scale, nmb) - 128;
        craw[img][c4][i * 7 + j] = q * q;
    }
    __syncthreads();
    if (tid < NIMG * 4) {   // 2D prefix sums, one thread per (img,corner)
        int img = tid >> 2, c4 = tid & 3;
        for (int r = 0; r < 8; ++r)
            for (int c = 0; c < 8; ++c) {
                int v = 0;
                if (r && c)
                    v = cps[img][c4][r - 1][c] + cps[img][c4][r][c - 1]
                      - cps[img][c4][r - 1][c - 1] + craw[img][c4][(r - 1) * 7 + (c - 1)];
                cps[img][c4][r][c] = v;
            }
    }
    __syncthreads();
    if (tid < NIMG * NOFF) {
        const int ORO[16] = {0,1,1,1, 0,2,3,2, 0,4,5,4, 0,5,7,5};
        const int OCO[16] = {1,1,0,-1, 3,2,0,-2, 5,4,0,-4, 7,5,0,-5};
        int img = tid >> 4, k = tid & 15;
        int orr = ORO[k], oc = OCO[k], aoc = oc < 0 ? -oc : oc;
        long long RT = 0, RB = 0, CL = 0, CR = 0;
        for (int i = 0; i < orr; ++i) { RT += RowS[img * 14 + i]; RB += RowS[img * 14 + 13 - i]; }
        for (int i = 0; i < aoc; ++i) { CL += ColS[img * 14 + i]; CR += ColS[img * 14 + 13 - i]; }
        long long CA = oc > 0 ? CR : CL;
        long long CB = oc > 0 ? CL : CR;
        long long PSa = (oc >= 0) ? cps[img][3][orr][aoc] : cps[img][2][orr][aoc];
        long long PSb = (oc >= 0) ? cps[img][0][orr][aoc] : cps[img][1][orr][aoc];
        long long corr = -(RT + RB + CA + CB) + PSa + PSb;
        long long cross = (long long)gacc[img * NACC + k];
        long long tsum  = (long long)gacc[img * NACC + 16];
        long long num = 2 * tsum + corr - 2 * cross;
        double n = (double)(H - orr) * (double)(W - aoc);
        out[tid] = (float)((double)num / n);
    }
}

extern "C" void kernel_launch(void* const* d_in, const int* in_sizes, int n_in,
                              void* d_out, int out_size, void* d_ws, size_t ws_size,
                              hipStream_t stream) {
    const float* x = (const float*)d_in[0];
    float* out = (float*)d_out;
    char* ws = (char*)d_ws;
    float* pmn = (float*)ws;                                       // 2048 f
    float* pmx = (float*)(ws + 8192);                              // 2048 f
    float* mnscale = (float*)(ws + 16384);                         // 64 f
    unsigned long long* gacc = (unsigned long long*)(ws + 16640);  // 32*17 u64
    int* RowS = (int*)(ws + 20992);                                // 32*14 int
    int* ColS = (int*)(ws + 22784);                                // 32*14 int

    minmax_partial<<<dim3(64, NIMG), 256, 0, stream>>>(x, pmn, pmx, gacc, RowS, ColS);
    minmax_final<<<NIMG, 64, 0, stream>>>(pmn, pmx, mnscale);
    band_sums<<<dim3(16, NIMG), 256, 0, stream>>>(x, mnscale, RowS, ColS);
    glcm_main<<<dim3(W / TW, H / TH, NIMG), 256, 0, stream>>>(x, mnscale, gacc);
    finalize_k<<<1, 512, 0, stream>>>(x, mnscale, gacc, RowS, ColS, out);
}

// Round 4
// 229.919 us; speedup vs baseline: 1.4197x; 1.2779x over previous
//
#include <hip/hip_runtime.h>

#define H 1024
#define W 1024
#define NIMG 32
#define NOFF 16
#define NACC 17          // 16 cross terms + 1 sum(s^2)
#define TH 32            // owned rows per block
#define TW 256           // owned cols per block
#define TROWS 39         // 32 + 7 halo rows (down only)
#define TSTR 304         // LDS row stride bytes

__device__ __forceinline__ int sdot4i(unsigned a, unsigned b, int c) {
#if __has_builtin(__builtin_amdgcn_sdot4)
    return __builtin_amdgcn_sdot4((int)a, (int)b, c, false);
#else
    c += (int)(signed char)(a)       * (int)(signed char)(b);
    c += (int)(signed char)(a >> 8)  * (int)(signed char)(b >> 8);
    c += (int)(signed char)(a >> 16) * (int)(signed char)(b >> 16);
    c += (int)(signed char)(a >> 24) * (int)(signed char)(b >> 24);
    return c;
#endif
}

__device__ __forceinline__ unsigned funnel(unsigned hi, unsigned lo, int shiftBytes) {
#if __has_builtin(__builtin_amdgcn_alignbit)
    return __builtin_amdgcn_alignbit(hi, lo, shiftBytes * 8);
#else
    unsigned long long pair = (((unsigned long long)hi) << 32) | lo;
    return (unsigned)(pair >> (shiftBytes * 8));
#endif
}

// wave64 sum via DPP butterfly: total lands in lane 63 (pure VALU, no LDS).
__device__ __forceinline__ int wave_sum(int v) {
    v += __builtin_amdgcn_update_dpp(0, v, 0x111, 0xf, 0xf, false); // row_shr:1
    v += __builtin_amdgcn_update_dpp(0, v, 0x112, 0xf, 0xf, false); // row_shr:2
    v += __builtin_amdgcn_update_dpp(0, v, 0x114, 0xf, 0xf, false); // row_shr:4
    v += __builtin_amdgcn_update_dpp(0, v, 0x118, 0xf, 0xf, false); // row_shr:8
    v += __builtin_amdgcn_update_dpp(0, v, 0x142, 0xa, 0xf, false); // row_bcast:15
    v += __builtin_amdgcn_update_dpp(0, v, 0x143, 0xc, 0xf, false); // row_bcast:31
    return v;
}

// dot of 32 'a' pixels (aw[0..7]) against window bytes starting at S=16+4m+OC.
template <int OC>
__device__ __forceinline__ int dot8(const unsigned* w, const unsigned* aw, int acc) {
#pragma unroll
    for (int m = 0; m < 8; ++m) {
        const int S = 16 + 4 * m + OC;
        unsigned b;
        if ((S & 3) == 0) b = w[S >> 2];
        else              b = funnel(w[(S >> 2) + 1], w[S >> 2], S & 3);
        acc = sdot4i(aw[m], b, acc);
    }
    return acc;
}

// scalar-component assignment only (vector punning into scalar arrays kills SROA)
__device__ __forceinline__ void load16w(const unsigned char* wp, unsigned* w) {
    uint4 t0 = *(const uint4*)(wp);
    uint4 t1 = *(const uint4*)(wp + 16);
    uint4 t2 = *(const uint4*)(wp + 32);
    uint4 t3 = *(const uint4*)(wp + 48);
    w[0] = t0.x;  w[1] = t0.y;  w[2] = t0.z;  w[3] = t0.w;
    w[4] = t1.x;  w[5] = t1.y;  w[6] = t1.z;  w[7] = t1.w;
    w[8] = t2.x;  w[9] = t2.y;  w[10] = t2.z; w[11] = t2.w;
    w[12] = t3.x; w[13] = t3.y; w[14] = t3.z; w[15] = t3.w;
}

__device__ __forceinline__ void load8mid(const unsigned char* wp, unsigned* w) {
    uint4 t1 = *(const uint4*)(wp + 16);
    uint4 t2 = *(const uint4*)(wp + 32);
    w[4] = t1.x;  w[5] = t1.y;  w[6] = t1.z;  w[7] = t1.w;
    w[8] = t2.x;  w[9] = t2.y;  w[10] = t2.z; w[11] = t2.w;
}

__device__ __forceinline__ unsigned pack4(float4 f, float s, float b) {
    unsigned q0 = (unsigned)(int)fmaf(f.x, s, b);
    unsigned q1 = (unsigned)(int)fmaf(f.y, s, b);
    unsigned q2 = (unsigned)(int)fmaf(f.z, s, b);
    unsigned q3 = (unsigned)(int)fmaf(f.w, s, b);
    return (((q0 & 255u)) | ((q1 & 255u) << 8) | ((q2 & 255u) << 16) | ((q3 & 255u) << 24)) ^ 0x80808080u;
}

// ---------------- kernel 1: per-image min/max partials + zero ws accums -------
__global__ __launch_bounds__(256)
void minmax_partial(const float* __restrict__ x, float* __restrict__ pmn,
                    float* __restrict__ pmx, unsigned long long* __restrict__ gacc,
                    int* __restrict__ RowS, int* __restrict__ ColS) {
    int img = blockIdx.y;
    int chunk = blockIdx.x;             // 64 chunks of 16384 floats
    int tid = threadIdx.x;
    if (chunk == 0) {                   // ws is poisoned each launch: zero here
        if (tid < NACC) gacc[img * NACC + tid] = 0ull;
        if (tid >= 32 && tid < 46) RowS[img * 14 + tid - 32] = 0;
        if (tid >= 64 && tid < 78) ColS[img * 14 + tid - 64] = 0;
    }
    const float4* b4 = (const float4*)(x + (size_t)img * (H * (size_t)W) +
                                       (size_t)chunk * (H * W / 64));
    float mn = INFINITY, mx = -INFINITY;
    for (int i = tid; i < 4096; i += 256) {
        float4 v = b4[i];
        mn = fminf(mn, fminf(fminf(v.x, v.y), fminf(v.z, v.w)));
        mx = fmaxf(mx, fmaxf(fmaxf(v.x, v.y), fmaxf(v.z, v.w)));
    }
    for (int o = 32; o > 0; o >>= 1) {
        mn = fminf(mn, __shfl_down(mn, o, 64));
        mx = fmaxf(mx, __shfl_down(mx, o, 64));
    }
    __shared__ float smn[4], smx[4];
    int wave = tid >> 6, lane = tid & 63;
    if (lane == 0) { smn[wave] = mn; smx[wave] = mx; }
    __syncthreads();
    if (tid == 0) {
        mn = fminf(fminf(smn[0], smn[1]), fminf(smn[2], smn[3]));
        mx = fmaxf(fmaxf(smx[0], smx[1]), fmaxf(smx[2], smx[3]));
        pmn[img * 64 + chunk] = mn;
        pmx[img * 64 + chunk] = mx;
    }
}

// ---------------- kernel 2: cross terms + s^2 + border bands/corners ----------
__global__ __launch_bounds__(256)
void glcm_main(const float* __restrict__ x, const float* __restrict__ pmn,
               const float* __restrict__ pmx, unsigned long long* __restrict__ gacc,
               int* __restrict__ RowS, int* __restrict__ ColS,
               short* __restrict__ cornerWS) {
    __shared__ __align__(16) unsigned char tile[TROWS * TSTR];
    __shared__ int wsum[4][NACC];
    __shared__ int sRB[7], sCB[7];
    __shared__ float sms[2];
    int tid = threadIdx.x;
    int img = blockIdx.z;
    int gr0 = blockIdx.y * TH;
    int gc0 = blockIdx.x * TW;

    // per-block min/max finalize (identical op order every block -> identical scale)
    if (tid < 64) {
        float mn = pmn[img * 64 + tid], mx = pmx[img * 64 + tid];
        for (int o = 32; o > 0; o >>= 1) {
            mn = fminf(mn, __shfl_down(mn, o, 64));
            mx = fmaxf(mx, __shfl_down(mx, o, 64));
        }
        if (tid == 0) {
            float sc = 255.0f / (mx - mn);
            sms[0] = sc; sms[1] = -mn * sc;
        }
    }
    if (tid >= 64 && tid < 71) { sRB[tid - 64] = 0; sCB[tid - 64] = 0; }
    __syncthreads();
    float scale = sms[0], nmb = sms[1];
    const float* xi = x + (size_t)img * (H * (size_t)W);

    // stage rows gr0..gr0+38; LDS byte c <-> global col gc0-16+c; zero pad OOB
    for (int slot = tid; slot < TROWS * (TSTR / 16); slot += 256) {
        int rr = slot / (TSTR / 16);
        int cc = (slot - rr * (TSTR / 16)) * 16;
        int grow = gr0 + rr;
        int gcol = gc0 - 16 + cc;
        uint4 bytes = make_uint4(0u, 0u, 0u, 0u);
        if (grow < H && gcol >= 0 && gcol < W) {
            const float4* p = (const float4*)(xi + (size_t)grow * W + gcol);
            float4 f0 = p[0], f1 = p[1], f2 = p[2], f3 = p[3];
            bytes.x = pack4(f0, scale, nmb);
            bytes.y = pack4(f1, scale, nmb);
            bytes.z = pack4(f2, scale, nmb);
            bytes.w = pack4(f3, scale, nmb);
        }
        *(uint4*)(tile + rr * TSTR + cc) = bytes;
    }
    __syncthreads();

    int r = tid >> 3;             // 0..31
    int c0 = (tid & 7) * 32;      // 0..224
    const unsigned char* rowp = tile + r * TSTR + 16 + c0;   // 'a' pixels
    const unsigned char* wbase = tile + r * TSTR + c0;       // window byte S=0

    uint4 av0 = *(const uint4*)(rowp);
    uint4 av1 = *(const uint4*)(rowp + 16);
    unsigned aw[8];
    aw[0] = av0.x; aw[1] = av0.y; aw[2] = av0.z; aw[3] = av0.w;
    aw[4] = av1.x; aw[5] = av1.y; aw[6] = av1.z; aw[7] = av1.w;

    int acc[NACC];
#pragma unroll
    for (int k = 0; k < NACC; ++k) acc[k] = 0;
#pragma unroll
    for (int m = 0; m < 8; ++m) acc[16] = sdot4i(aw[m], aw[m], acc[16]);

    unsigned w[16];
    // delta = 0 : oc = 1,3,5,7  (w[4..11] == aw; w[12..15] for oc up to 7)
    {
#pragma unroll
        for (int i = 0; i < 8; ++i) w[4 + i] = aw[i];
        uint4 t3 = *(const uint4*)(wbase + 48);
        w[12] = t3.x; w[13] = t3.y; w[14] = t3.z; w[15] = t3.w;
        acc[0]  = dot8<1>(w, aw, acc[0]);
        acc[4]  = dot8<3>(w, aw, acc[4]);
        acc[8]  = dot8<5>(w, aw, acc[8]);
        acc[12] = dot8<7>(w, aw, acc[12]);
    }
    // delta = 1 : oc = 1,0,-1
    {
        load16w(wbase + 1 * TSTR, w);
        acc[1] = dot8<1>(w, aw, acc[1]);
        acc[2] = dot8<0>(w, aw, acc[2]);
        acc[3] = dot8<-1>(w, aw, acc[3]);
    }
    // delta = 2 : oc = 2,-2
    {
        load16w(wbase + 2 * TSTR, w);
        acc[5] = dot8<2>(w, aw, acc[5]);
        acc[7] = dot8<-2>(w, aw, acc[7]);
    }
    // delta = 3 : oc = 0
    {
        load8mid(wbase + 3 * TSTR, w);
        acc[6] = dot8<0>(w, aw, acc[6]);
    }
    // delta = 4 : oc = 4,-4
    {
        load16w(wbase + 4 * TSTR, w);
        acc[9]  = dot8<4>(w, aw, acc[9]);
        acc[11] = dot8<-4>(w, aw, acc[11]);
    }
    // delta = 5 : oc = 0,5,-5
    {
        load16w(wbase + 5 * TSTR, w);
        acc[10] = dot8<0>(w, aw, acc[10]);
        acc[13] = dot8<5>(w, aw, acc[13]);
        acc[15] = dot8<-5>(w, aw, acc[15]);
    }
    // delta = 7 : oc = 0
    {
        load8mid(wbase + 7 * TSTR, w);
        acc[14] = dot8<0>(w, aw, acc[14]);
    }

    // wave reduce via DPP (no LDS serialization), lane 63 holds totals
    int wv = tid >> 6, lane = tid & 63;
#pragma unroll
    for (int k = 0; k < NACC; ++k) {
        int t = wave_sum(acc[k]);
        if (lane == 63) wsum[wv][k] = t;
    }

    // border blocks: band sums of s^2 from the staged tile
    bool rowTop = (gr0 == 0), rowBot = (gr0 == H - TH);
    bool colLft = (gc0 == 0), colRgt = (gc0 == W - TW);
    if (rowTop || rowBot) {
        int base = rowTop ? 0 : 25;            // rows 0-6 or 1017-1023
        for (int idx = tid; idx < 7 * 64; idx += 256) {
            int rr = idx >> 6, ww = idx & 63;
            unsigned v = *(const unsigned*)(tile + (base + rr) * TSTR + 16 + 4 * ww);
            atomicAdd(&sRB[rr], sdot4i(v, v, 0));
        }
    }
    if (colLft || colRgt) {
        int cb = colLft ? 16 : 265;            // cols 0-6 or 1017-1023
        if (tid < 7 * TH) {
            int rr = tid / 7, j = tid - rr * 7;
            int s = (int)(signed char)tile[rr * TSTR + cb + j];
            atomicAdd(&sCB[j], s * s);
        }
    }
    // corner 7x7 s^2 patches -> ws (c4: 0=TL,1=TR,2=BL,3=BR, oriented to corner)
    if (tid < 49) {
        int i = tid / 7, j = tid - i * 7;
        if (rowTop && colLft) {
            int s = (int)(signed char)tile[i * TSTR + 16 + j];
            cornerWS[(img * 4 + 0) * 49 + tid] = (short)(s * s);
        }
        if (rowTop && colRgt) {
            int s = (int)(signed char)tile[i * TSTR + 271 - j];
            cornerWS[(img * 4 + 1) * 49 + tid] = (short)(s * s);
        }
        if (rowBot && colLft) {
            int s = (int)(signed char)tile[(31 - i) * TSTR + 16 + j];
            cornerWS[(img * 4 + 2) * 49 + tid] = (short)(s * s);
        }
        if (rowBot && colRgt) {
            int s = (int)(signed char)tile[(31 - i) * TSTR + 271 - j];
            cornerWS[(img * 4 + 3) * 49 + tid] = (short)(s * s);
        }
    }
    __syncthreads();
    if (tid < NACC) {
        int s = wsum[0][tid] + wsum[1][tid] + wsum[2][tid] + wsum[3][tid];
        atomicAdd(&gacc[img * NACC + tid], (unsigned long long)(long long)s);
    }
    if (tid < 7) {
        if (rowTop) atomicAdd(&RowS[img * 14 + tid], sRB[tid]);
        if (rowBot) atomicAdd(&RowS[img * 14 + 7 + tid], sRB[tid]);
        if (colLft) atomicAdd(&ColS[img * 14 + tid], sCB[tid]);
        if (colRgt) atomicAdd(&ColS[img * 14 + 7 + tid], sCB[tid]);
    }
}

// ---------------- kernel 3: corners prefix + combine --------------------------
__global__ __launch_bounds__(512)
void finalize_k(const unsigned long long* __restrict__ gacc,
                const int* __restrict__ RowS, const int* __restrict__ ColS,
                const short* __restrict__ cornerWS, float* __restrict__ out) {
    __shared__ int cps[NIMG][4][8][8];
    int tid = threadIdx.x;
    if (tid < NIMG * 4) {   // 2D prefix sums, one thread per (img,corner)
        int img = tid >> 2, c4 = tid & 3;
        const short* cr = cornerWS + (img * 4 + c4) * 49;
        for (int r = 0; r < 8; ++r)
            for (int c = 0; c < 8; ++c) {
                int v = 0;
                if (r && c)
                    v = cps[img][c4][r - 1][c] + cps[img][c4][r][c - 1]
                      - cps[img][c4][r - 1][c - 1] + (int)cr[(r - 1) * 7 + (c - 1)];
                cps[img][c4][r][c] = v;
            }
    }
    __syncthreads();
    if (tid < NIMG * NOFF) {
        const int ORO[16] = {0,1,1,1, 0,2,3,2, 0,4,5,4, 0,5,7,5};
        const int OCO[16] = {1,1,0,-1, 3,2,0,-2, 5,4,0,-4, 7,5,0,-5};
        int img = tid >> 4, k = tid & 15;
        int orr = ORO[k], oc = OCO[k], aoc = oc < 0 ? -oc : oc;
        long long RT = 0, RB = 0, CL = 0, CR = 0;
        for (int i = 0; i < orr; ++i) { RT += RowS[img * 14 + i]; RB += RowS[img * 14 + 13 - i]; }
        for (int i = 0; i < aoc; ++i) { CL += ColS[img * 14 + i]; CR += ColS[img * 14 + 13 - i]; }
        long long CA = oc > 0 ? CR : CL;
        long long CB = oc > 0 ? CL : CR;
        long long PSa = (oc >= 0) ? cps[img][3][orr][aoc] : cps[img][2][orr][aoc];
        long long PSb = (oc >= 0) ? cps[img][0][orr][aoc] : cps[img][1][orr][aoc];
        long long corr = -(RT + RB + CA + CB) + PSa + PSb;
        long long cross = (long long)gacc[img * NACC + k];
        long long tsum  = (long long)gacc[img * NACC + 16];
        long long num = 2 * tsum + corr - 2 * cross;
        double n = (double)(H - orr) * (double)(W - aoc);
        out[tid] = (float)((double)num / n);
    }
}

extern "C" void kernel_launch(void* const* d_in, const int* in_sizes, int n_in,
                              void* d_out, int out_size, void* d_ws, size_t ws_size,
                              hipStream_t stream) {
    const float* x = (const float*)d_in[0];
    float* out = (float*)d_out;
    char* ws = (char*)d_ws;
    float* pmn = (float*)ws;                                       // 2048 f   @0
    float* pmx = (float*)(ws + 8192);                              // 2048 f   @8192
    unsigned long long* gacc = (unsigned long long*)(ws + 16384);  // 32*17 u64 @16384
    int* RowS = (int*)(ws + 20736);                                // 32*14 int
    int* ColS = (int*)(ws + 22528);                                // 32*14 int
    short* cornerWS = (short*)(ws + 24320);                        // 32*4*49 short

    minmax_partial<<<dim3(64, NIMG), 256, 0, stream>>>(x, pmn, pmx, gacc, RowS, ColS);
    glcm_main<<<dim3(W / TW, H / TH, NIMG), 256, 0, stream>>>(x, pmn, pmx, gacc,
                                                              RowS, ColS, cornerWS);
    finalize_k<<<1, 512, 0, stream>>>(gacc, RowS, ColS, cornerWS, out);
}